// Round 3
// baseline (216.870 us; speedup 1.0000x reference)
//
#include <hip/hip_runtime.h>
#include <hip/hip_cooperative_groups.h>
#include <math.h>

namespace cg = cooperative_groups;

// Chamfer distance, N=16384 points per cloud (8*2048), 3-D fp32.
// d2(i,j) = n_i + n_j - 2*dot = n_i + 2*(c_j - dot),  c = 0.5*||p||^2
// Inner loop: 3 fma/pair + 1 v_min3 per 2 pairs = 3.5 VALU inst/pair.
// IP=8 so one uniform ds_read_b128 feeds 16 pairs -> LDS pipe (1/CU) no
// longer the limiter (R1 post-mortem: IP=4 was LDS-bound at 1.7x floor;
// derived VALUBusy is inflated ~2x by the gfx94x SIMD-16 formula).
// Single cooperative kernel: init -> sync -> min -> sync -> reduce.
#define N_PTS 16384
#define TPB   256
#define IP    8                       // query points per thread (registers)
#define IBLK  (N_PTS / (TPB * IP))    // 8 i-blocks
#define JT    512                     // target tile in LDS (8 KB)
#define JS    (N_PTS / JT)            // 32 j-splits, combined via atomicMin
#define GRID  (JS * IBLK * 2)        // 512 blocks = 2/CU (co-resident)

__global__ __launch_bounds__(TPB, 2) void chamfer_fused(
    const float* __restrict__ p1, const float* __restrict__ p2,
    unsigned int* __restrict__ dmin, float* __restrict__ outp) {
  cg::grid_group grid = cg::this_grid();
  __shared__ float4 tile[JT];
  const int bid = blockIdx.x;
  const int tid = threadIdx.x;

  // ---- Phase A: init. dmin = +huge bits (d2>=0 so uint order == float
  // order; 0x7F7F7F7F = 3.39e38f). outp zeroed via device-scope atomic.
  {
    const int per = 2 * N_PTS / GRID;            // 64
    if (tid < per) dmin[bid * per + tid] = 0x7F7F7F7Fu;
    if (bid == 0 && tid == 0) atomicExch(outp, 0.0f);
  }
  grid.sync();

  // ---- Phase B: tiled min.
  const int js  = bid & (JS - 1);
  const int ib  = (bid >> 5) & (IBLK - 1);
  const int dir = bid >> 8;                      // 0: Q=pc1,T=pc2
  const float* __restrict__ Qraw = dir ? p2 : p1;
  const float* __restrict__ Traw = dir ? p1 : p2;

  // Pack this block's target tile (raw xyz -> xyz + 0.5*|p|^2).
  const int jbase = js * JT;
  for (int t = tid; t < JT; t += TPB) {
    float x = Traw[3 * (jbase + t) + 0];
    float y = Traw[3 * (jbase + t) + 1];
    float z = Traw[3 * (jbase + t) + 2];
    tile[t] = make_float4(x, y, z, 0.5f * (x * x + y * y + z * z));
  }
  __syncthreads();

  // Load IP query points: 24 contiguous floats/thread, 16B-aligned.
  const int i0 = ib * (TPB * IP) + tid * IP;
  float f[24];
  const float4* __restrict__ Qv = (const float4*)(Qraw + 3 * i0);
#pragma unroll
  for (int t = 0; t < 6; ++t) {
    float4 v = Qv[t];
    f[4 * t] = v.x; f[4 * t + 1] = v.y; f[4 * t + 2] = v.z; f[4 * t + 3] = v.w;
  }
  float nx[IP], ny[IP], nz[IP], cw[IP], vmin[IP];
#pragma unroll
  for (int k = 0; k < IP; ++k) {
    float x = f[3 * k], y = f[3 * k + 1], z = f[3 * k + 2];
    nx[k] = -x; ny[k] = -y; nz[k] = -z;
    cw[k] = 0.5f * (x * x + y * y + z * z);
    vmin[k] = 3.0e38f;
  }

  // min_j (c_j - dot_ij); h_i drops out of the argmin.
#pragma unroll 8
  for (int j = 0; j < JT; j += 2) {
    float4 qa = tile[j];
    float4 qb = tile[j + 1];
#pragma unroll
    for (int k = 0; k < IP; ++k) {
      float va = fmaf(nx[k], qa.x, qa.w);
      va = fmaf(ny[k], qa.y, va);
      va = fmaf(nz[k], qa.z, va);
      float vb = fmaf(nx[k], qb.x, qb.w);
      vb = fmaf(ny[k], qb.y, vb);
      vb = fmaf(nz[k], qb.z, vb);
      // vmin = min(vmin, va, vb) in ONE instruction (data is NaN-free;
      // fminf would emit v_max canonicalization + no min3 formation).
      asm("v_min3_f32 %0, %1, %2, %0" : "+v"(vmin[k]) : "v"(va), "v"(vb));
    }
  }

  unsigned int* __restrict__ out = dmin + (size_t)dir * N_PTS;
#pragma unroll
  for (int k = 0; k < IP; ++k) {
    float d2 = fmaxf(0.f, 2.f * (cw[k] + vmin[k]));   // clamp -> non-negative
    atomicMin(&out[i0 + k], __float_as_uint(d2));     // monotone on uint bits
  }
  grid.sync();

  // ---- Phase C: block-parallel sqrt-sum. Each block owns 64 entries
  // (one wave), butterfly-reduces, one atomicAdd per block.
  if (tid < 64) {
    float s = sqrtf(__uint_as_float(dmin[bid * 64 + tid]));
#pragma unroll
    for (int off = 32; off > 0; off >>= 1)
      s += __shfl_down(s, off, 64);
    if (tid == 0)
      atomicAdd(outp, s * (1.0f / (float)N_PTS));  // sum(all 2N)/N = mean1+mean2
  }
}

extern "C" void kernel_launch(void* const* d_in, const int* in_sizes, int n_in,
                              void* d_out, int out_size, void* d_ws, size_t ws_size,
                              hipStream_t stream) {
  const float* pc1 = (const float*)d_in[0];
  const float* pc2 = (const float*)d_in[1];
  unsigned int* dmin = (unsigned int*)d_ws;        // 128 KB
  float* outp = (float*)d_out;

  void* args[] = {(void*)&pc1, (void*)&pc2, (void*)&dmin, (void*)&outp};
  hipLaunchCooperativeKernel((void*)chamfer_fused, dim3(GRID), dim3(TPB),
                             args, 0, stream);
}

// Round 4
// 111.791 us; speedup vs baseline: 1.9400x; 1.9400x over previous
//
#include <hip/hip_runtime.h>
#include <math.h>

// Chamfer distance, N=16384 points per cloud (8*2048), 3-D fp32.
// d2(i,j) = n_i + n_j - 2*dot = n_i + 2*(c_j - dot),  c = 0.5*||p||^2
// Inner loop: 3 fma/pair + 1 v_min3 per 2 pairs = 3.5 VALU inst/pair.
// IP=8: one broadcast ds_read_b128 feeds 16 pairs -> VALU-bound
// (IP=4 was LDS-pipe-bound: 96 LDS cyc vs 56 VALU cyc per 2-j iter).
// NOTE R3 post-mortem: fused cooperative version spilled all per-thread
// arrays to scratch (VGPR 28, 33MB scratch writes) -> keep this exact
// 3-kernel structure whose codegen is verified clean (VGPR 48 @ IP=4).
#define N_PTS 16384
#define TPB   256
#define IP    8                       // query points per thread (registers)
#define IBLK  (N_PTS / (TPB * IP))    // 8 i-blocks
#define JT    512                     // tile in LDS (8 KB)
#define JS    (N_PTS / JT)            // 32 j-splits, combined via atomicMin
#define REDB  64                      // reduce blocks

__global__ __launch_bounds__(TPB) void chamfer_pack(
    const float* __restrict__ p1, const float* __restrict__ p2,
    float4* __restrict__ P, unsigned int* __restrict__ dmin,
    float* __restrict__ outp) {
  int id = blockIdx.x * TPB + threadIdx.x;          // 0 .. 2*N_PTS-1
  const float* src = (id < N_PTS) ? p1 : p2;
  int k = (id < N_PTS) ? id : (id - N_PTS);
  float x = src[3 * k + 0], y = src[3 * k + 1], z = src[3 * k + 2];
  P[id] = make_float4(x, y, z, 0.5f * (x * x + y * y + z * z));
  dmin[id] = 0x7F800000u;  // +inf bits (d2 >= 0, so uint order == float order)
  if (id == 0) outp[0] = 0.f;        // harness poisons d_out with 0xAA
}

__global__ __launch_bounds__(TPB) void chamfer_min(
    const float4* __restrict__ P, unsigned int* __restrict__ dmin) {
  __shared__ float4 tile[JT];
  const int dir = blockIdx.z;                         // 0: query=pc1, 1: query=pc2
  const float4* __restrict__ Q = P + (size_t)dir * N_PTS;
  const float4* __restrict__ T = P + (size_t)(1 - dir) * N_PTS;
  unsigned int* __restrict__ out = dmin + (size_t)dir * N_PTS;

  const int jbase = blockIdx.x * JT;
  for (int t = threadIdx.x; t < JT; t += TPB)
    tile[t] = T[jbase + t];
  __syncthreads();

  const int i0 = blockIdx.y * (TPB * IP) + threadIdx.x * IP;
  float nx[IP], ny[IP], nz[IP], cw[IP], vmin[IP];
#pragma unroll
  for (int k = 0; k < IP; ++k) {
    float4 p = Q[i0 + k];
    nx[k] = -p.x; ny[k] = -p.y; nz[k] = -p.z; cw[k] = p.w;
    vmin[k] = 3.0e38f;
  }

  // min_j (c_j - dot_ij); h_i drops out of the argmin.
#pragma unroll 8
  for (int j = 0; j < JT; j += 2) {
    float4 qa = tile[j];
    float4 qb = tile[j + 1];
#pragma unroll
    for (int k = 0; k < IP; ++k) {
      float va = fmaf(nx[k], qa.x, qa.w);
      va = fmaf(ny[k], qa.y, va);
      va = fmaf(nz[k], qa.z, va);
      float vb = fmaf(nx[k], qb.x, qb.w);
      vb = fmaf(ny[k], qb.y, vb);
      vb = fmaf(nz[k], qb.z, vb);
      // vmin = min(vmin, va, vb) in ONE instruction (data is NaN-free;
      // fminf would emit v_max canonicalization + no min3 formation).
      asm("v_min3_f32 %0, %1, %2, %0" : "+v"(vmin[k]) : "v"(va), "v"(vb));
    }
  }

#pragma unroll
  for (int k = 0; k < IP; ++k) {
    float d2 = fmaxf(0.f, 2.f * (cw[k] + vmin[k]));   // clamp -> non-negative
    atomicMin(&out[i0 + k], __float_as_uint(d2));     // monotone on uint bits
  }
}

__global__ __launch_bounds__(TPB) void chamfer_reduce(
    const unsigned int* __restrict__ dmin, float* __restrict__ outp) {
  float s = 0.f;
  for (int i = blockIdx.x * TPB + threadIdx.x; i < 2 * N_PTS; i += REDB * TPB)
    s += sqrtf(__uint_as_float(dmin[i]));
#pragma unroll
  for (int off = 32; off > 0; off >>= 1)
    s += __shfl_down(s, off, 64);
  __shared__ float partial[TPB / 64];
  if ((threadIdx.x & 63) == 0) partial[threadIdx.x >> 6] = s;
  __syncthreads();
  if (threadIdx.x == 0) {
    float t = 0.f;
    for (int w = 0; w < TPB / 64; ++w) t += partial[w];
    // mean(dist1) + mean(dist2) = (sum of all 2N nn-distances) / N
    atomicAdd(outp, t * (1.0f / (float)N_PTS));
  }
}

extern "C" void kernel_launch(void* const* d_in, const int* in_sizes, int n_in,
                              void* d_out, int out_size, void* d_ws, size_t ws_size,
                              hipStream_t stream) {
  const float* pc1 = (const float*)d_in[0];
  const float* pc2 = (const float*)d_in[1];
  // ws layout: P[2N] float4 (512 KB) | dmin[2N] uint (128 KB)
  float4* P = (float4*)d_ws;
  unsigned int* dmin = (unsigned int*)((char*)d_ws + (size_t)2 * N_PTS * sizeof(float4));
  float* outp = (float*)d_out;

  chamfer_pack<<<(2 * N_PTS) / TPB, TPB, 0, stream>>>(pc1, pc2, P, dmin, outp);
  chamfer_min<<<dim3(JS, IBLK, 2), TPB, 0, stream>>>(P, dmin);
  chamfer_reduce<<<REDB, TPB, 0, stream>>>(dmin, outp);
}

// Round 5
// 111.423 us; speedup vs baseline: 1.9464x; 1.0033x over previous
//
#include <hip/hip_runtime.h>
#include <math.h>

// Chamfer distance, N=16384 points per cloud (8*2048), 3-D fp32.
// d2(i,j) = n_i + n_j - 2*dot = n_i + 2*(c_j - dot),  c = 0.5*||p||^2
// Inner loop: 3 fma/pair + 1 v_min3 per 2 pairs = 3.5 VALU inst/pair.
// IP=8: one broadcast ds_read_b128 feeds 16 pairs; per CU-round VALU
// 28W cyc vs LDS-pipe 24W cyc -> VALU-bound (IP=4 was LDS-bound 1.7x).
// R4 post-mortem: __launch_bounds__(256) alone let the backend target
// 8 waves/EU -> ~64-VGPR budget -> full spill of the k-arrays (VGPR=32,
// WRITE_SIZE = 32 MB = 256 B/thread scratch frame, 62 us). Fix: declare
// (256,2) = 2 waves/EU = 2 blocks/CU (matches the 512-block grid), cap
// 256 VGPRs -> arrays stay in registers.
#define N_PTS 16384
#define TPB   256
#define IP    8                       // query points per thread (registers)
#define IBLK  (N_PTS / (TPB * IP))    // 8 i-blocks
#define JT    512                     // tile in LDS (8 KB)
#define JS    (N_PTS / JT)            // 32 j-splits, combined via atomicMin
#define REDB  64                      // reduce blocks

__global__ __launch_bounds__(TPB) void chamfer_pack(
    const float* __restrict__ p1, const float* __restrict__ p2,
    float4* __restrict__ P, unsigned int* __restrict__ dmin,
    float* __restrict__ outp) {
  int id = blockIdx.x * TPB + threadIdx.x;          // 0 .. 2*N_PTS-1
  const float* src = (id < N_PTS) ? p1 : p2;
  int k = (id < N_PTS) ? id : (id - N_PTS);
  float x = src[3 * k + 0], y = src[3 * k + 1], z = src[3 * k + 2];
  P[id] = make_float4(x, y, z, 0.5f * (x * x + y * y + z * z));
  dmin[id] = 0x7F800000u;  // +inf bits (d2 >= 0, so uint order == float order)
  if (id == 0) outp[0] = 0.f;        // harness poisons d_out with 0xAA
}

__global__ __launch_bounds__(TPB, 2) void chamfer_min(
    const float4* __restrict__ P, unsigned int* __restrict__ dmin) {
  __shared__ float4 tile[JT];
  const int dir = blockIdx.z;                         // 0: query=pc1, 1: query=pc2
  const float4* __restrict__ Q = P + (size_t)dir * N_PTS;
  const float4* __restrict__ T = P + (size_t)(1 - dir) * N_PTS;
  unsigned int* __restrict__ out = dmin + (size_t)dir * N_PTS;

  const int jbase = blockIdx.x * JT;
  for (int t = threadIdx.x; t < JT; t += TPB)
    tile[t] = T[jbase + t];
  __syncthreads();

  const int i0 = blockIdx.y * (TPB * IP) + threadIdx.x * IP;
  float nx[IP], ny[IP], nz[IP], cw[IP], vmin[IP];
#pragma unroll
  for (int k = 0; k < IP; ++k) {
    float4 p = Q[i0 + k];
    nx[k] = -p.x; ny[k] = -p.y; nz[k] = -p.z; cw[k] = p.w;
    vmin[k] = 3.0e38f;
  }

  // min_j (c_j - dot_ij); h_i drops out of the argmin.
#pragma unroll 8
  for (int j = 0; j < JT; j += 2) {
    float4 qa = tile[j];
    float4 qb = tile[j + 1];
#pragma unroll
    for (int k = 0; k < IP; ++k) {
      float va = fmaf(nx[k], qa.x, qa.w);
      va = fmaf(ny[k], qa.y, va);
      va = fmaf(nz[k], qa.z, va);
      float vb = fmaf(nx[k], qb.x, qb.w);
      vb = fmaf(ny[k], qb.y, vb);
      vb = fmaf(nz[k], qb.z, vb);
      // vmin = min(vmin, va, vb) in ONE instruction (data is NaN-free;
      // fminf would emit v_max canonicalization + no min3 formation).
      asm("v_min3_f32 %0, %1, %2, %0" : "+v"(vmin[k]) : "v"(va), "v"(vb));
    }
  }

#pragma unroll
  for (int k = 0; k < IP; ++k) {
    float d2 = fmaxf(0.f, 2.f * (cw[k] + vmin[k]));   // clamp -> non-negative
    atomicMin(&out[i0 + k], __float_as_uint(d2));     // monotone on uint bits
  }
}

__global__ __launch_bounds__(TPB) void chamfer_reduce(
    const unsigned int* __restrict__ dmin, float* __restrict__ outp) {
  float s = 0.f;
  for (int i = blockIdx.x * TPB + threadIdx.x; i < 2 * N_PTS; i += REDB * TPB)
    s += sqrtf(__uint_as_float(dmin[i]));
#pragma unroll
  for (int off = 32; off > 0; off >>= 1)
    s += __shfl_down(s, off, 64);
  __shared__ float partial[TPB / 64];
  if ((threadIdx.x & 63) == 0) partial[threadIdx.x >> 6] = s;
  __syncthreads();
  if (threadIdx.x == 0) {
    float t = 0.f;
    for (int w = 0; w < TPB / 64; ++w) t += partial[w];
    // mean(dist1) + mean(dist2) = (sum of all 2N nn-distances) / N
    atomicAdd(outp, t * (1.0f / (float)N_PTS));
  }
}

extern "C" void kernel_launch(void* const* d_in, const int* in_sizes, int n_in,
                              void* d_out, int out_size, void* d_ws, size_t ws_size,
                              hipStream_t stream) {
  const float* pc1 = (const float*)d_in[0];
  const float* pc2 = (const float*)d_in[1];
  // ws layout: P[2N] float4 (512 KB) | dmin[2N] uint (128 KB)
  float4* P = (float4*)d_ws;
  unsigned int* dmin = (unsigned int*)((char*)d_ws + (size_t)2 * N_PTS * sizeof(float4));
  float* outp = (float*)d_out;

  chamfer_pack<<<(2 * N_PTS) / TPB, TPB, 0, stream>>>(pc1, pc2, P, dmin, outp);
  chamfer_min<<<dim3(JS, IBLK, 2), TPB, 0, stream>>>(P, dmin);
  chamfer_reduce<<<REDB, TPB, 0, stream>>>(dmin, outp);
}

// Round 6
// 109.359 us; speedup vs baseline: 1.9831x; 1.0189x over previous
//
#include <hip/hip_runtime.h>
#include <math.h>

// Chamfer distance, N=16384 points per cloud (8*2048), 3-D fp32.
// d2(i,j) = n_i + n_j - 2*dot = n_i + 2*(c_j - dot),  c = 0.5*||p||^2
// Inner loop: 3 fma/pair + 1 v_min3 per 2 pairs = 3.5 VALU inst/pair.
// IP=8: one broadcast ds_read_b128 feeds 16 pairs; per CU-round VALU
// 224 cyc vs LDS-pipe 192 cyc -> VALU-bound at ~85% util.
// R5 post-mortem: __launch_bounds__(256,2) sets only the MIN of
// amdgpu-waves-per-eu; the allocator still chased its max-occupancy
// heuristic and spilled a 256 B/thread frame (VGPR=32, WRITE_SIZE
// = 32 MB = exactly 131072 threads x 256 B). Fix: pin min=max=2
// waves/EU -> VGPR budget 256 -> k-arrays live in registers.
#define N_PTS 16384
#define TPB   256
#define IP    8                       // query points per thread (registers)
#define IBLK  (N_PTS / (TPB * IP))    // 8 i-blocks
#define JT    512                     // tile in LDS (8 KB)
#define JS    (N_PTS / JT)            // 32 j-splits, combined via atomicMin
#define REDB  64                      // reduce blocks

__global__ __launch_bounds__(TPB) void chamfer_pack(
    const float* __restrict__ p1, const float* __restrict__ p2,
    float4* __restrict__ P, unsigned int* __restrict__ dmin,
    float* __restrict__ outp) {
  int id = blockIdx.x * TPB + threadIdx.x;          // 0 .. 2*N_PTS-1
  const float* src = (id < N_PTS) ? p1 : p2;
  int k = (id < N_PTS) ? id : (id - N_PTS);
  float x = src[3 * k + 0], y = src[3 * k + 1], z = src[3 * k + 2];
  P[id] = make_float4(x, y, z, 0.5f * (x * x + y * y + z * z));
  dmin[id] = 0x7F800000u;  // +inf bits (d2 >= 0, so uint order == float order)
  if (id == 0) outp[0] = 0.f;        // harness poisons d_out with 0xAA
}

__global__ __launch_bounds__(TPB)
__attribute__((amdgpu_waves_per_eu(2, 2)))   // pin target: 256-VGPR budget
void chamfer_min(
    const float4* __restrict__ P, unsigned int* __restrict__ dmin) {
  __shared__ float4 tile[JT];
  const int dir = blockIdx.z;                         // 0: query=pc1, 1: query=pc2
  const float4* __restrict__ Q = P + (size_t)dir * N_PTS;
  const float4* __restrict__ T = P + (size_t)(1 - dir) * N_PTS;
  unsigned int* __restrict__ out = dmin + (size_t)dir * N_PTS;

  const int jbase = blockIdx.x * JT;
  for (int t = threadIdx.x; t < JT; t += TPB)
    tile[t] = T[jbase + t];
  __syncthreads();

  const int i0 = blockIdx.y * (TPB * IP) + threadIdx.x * IP;
  float nx[IP], ny[IP], nz[IP], cw[IP], vmin[IP];
#pragma unroll
  for (int k = 0; k < IP; ++k) {
    float4 p = Q[i0 + k];
    nx[k] = -p.x; ny[k] = -p.y; nz[k] = -p.z; cw[k] = p.w;
    vmin[k] = 3.0e38f;
  }

  // min_j (c_j - dot_ij); h_i drops out of the argmin.
#pragma unroll 8
  for (int j = 0; j < JT; j += 2) {
    float4 qa = tile[j];
    float4 qb = tile[j + 1];
#pragma unroll
    for (int k = 0; k < IP; ++k) {
      float va = fmaf(nx[k], qa.x, qa.w);
      va = fmaf(ny[k], qa.y, va);
      va = fmaf(nz[k], qa.z, va);
      float vb = fmaf(nx[k], qb.x, qb.w);
      vb = fmaf(ny[k], qb.y, vb);
      vb = fmaf(nz[k], qb.z, vb);
      // vmin = min(vmin, va, vb) in ONE instruction (data is NaN-free;
      // fminf would emit v_max canonicalization + no min3 formation).
      asm("v_min3_f32 %0, %1, %2, %0" : "+v"(vmin[k]) : "v"(va), "v"(vb));
    }
  }

#pragma unroll
  for (int k = 0; k < IP; ++k) {
    float d2 = fmaxf(0.f, 2.f * (cw[k] + vmin[k]));   // clamp -> non-negative
    atomicMin(&out[i0 + k], __float_as_uint(d2));     // monotone on uint bits
  }
}

__global__ __launch_bounds__(TPB) void chamfer_reduce(
    const unsigned int* __restrict__ dmin, float* __restrict__ outp) {
  float s = 0.f;
  for (int i = blockIdx.x * TPB + threadIdx.x; i < 2 * N_PTS; i += REDB * TPB)
    s += sqrtf(__uint_as_float(dmin[i]));
#pragma unroll
  for (int off = 32; off > 0; off >>= 1)
    s += __shfl_down(s, off, 64);
  __shared__ float partial[TPB / 64];
  if ((threadIdx.x & 63) == 0) partial[threadIdx.x >> 6] = s;
  __syncthreads();
  if (threadIdx.x == 0) {
    float t = 0.f;
    for (int w = 0; w < TPB / 64; ++w) t += partial[w];
    // mean(dist1) + mean(dist2) = (sum of all 2N nn-distances) / N
    atomicAdd(outp, t * (1.0f / (float)N_PTS));
  }
}

extern "C" void kernel_launch(void* const* d_in, const int* in_sizes, int n_in,
                              void* d_out, int out_size, void* d_ws, size_t ws_size,
                              hipStream_t stream) {
  const float* pc1 = (const float*)d_in[0];
  const float* pc2 = (const float*)d_in[1];
  // ws layout: P[2N] float4 (512 KB) | dmin[2N] uint (128 KB)
  float4* P = (float4*)d_ws;
  unsigned int* dmin = (unsigned int*)((char*)d_ws + (size_t)2 * N_PTS * sizeof(float4));
  float* outp = (float*)d_out;

  chamfer_pack<<<(2 * N_PTS) / TPB, TPB, 0, stream>>>(pc1, pc2, P, dmin, outp);
  chamfer_min<<<dim3(JS, IBLK, 2), TPB, 0, stream>>>(P, dmin);
  chamfer_reduce<<<REDB, TPB, 0, stream>>>(dmin, outp);
}

// Round 7
// 108.321 us; speedup vs baseline: 2.0021x; 1.0096x over previous
//
#include <hip/hip_runtime.h>
#include <math.h>

// Chamfer distance, N=16384 points per cloud (8*2048), 3-D fp32.
// d2(i,j) = n_i + n_j - 2*dot = n_i + 2*(c_j - dot),  c = 0.5*||p||^2
// Inner loop: 3 fma/pair + 1 v_min3 per 2 pairs = 3.5 VALU inst/pair.
// R6 post-mortem: VGPR 32->104 (waves_per_eu pin applied) yet WRITE_SIZE
// stayed exactly 131072 thr x 256 B and dur unchanged -> the k-arrays
// were never SROA-promoted; the scratch alloca survives regardless of
// VGPR budget. Fix: NO ARRAYS — 40 named scalars via macros, so the
// state cannot live anywhere but registers.
#define N_PTS 16384
#define TPB   256
#define IP    8                       // query points per thread (named scalars)
#define IBLK  (N_PTS / (TPB * IP))    // 8 i-blocks
#define JT    512                     // tile in LDS (8 KB)
#define JS    (N_PTS / JT)            // 32 j-splits, combined via atomicMin
#define REDB  64                      // reduce blocks

__global__ __launch_bounds__(TPB) void chamfer_pack(
    const float* __restrict__ p1, const float* __restrict__ p2,
    float4* __restrict__ P, unsigned int* __restrict__ dmin,
    float* __restrict__ outp) {
  int id = blockIdx.x * TPB + threadIdx.x;          // 0 .. 2*N_PTS-1
  const float* src = (id < N_PTS) ? p1 : p2;
  int k = (id < N_PTS) ? id : (id - N_PTS);
  float x = src[3 * k + 0], y = src[3 * k + 1], z = src[3 * k + 2];
  P[id] = make_float4(x, y, z, 0.5f * (x * x + y * y + z * z));
  dmin[id] = 0x7F800000u;  // +inf bits (d2 >= 0, so uint order == float order)
  if (id == 0) outp[0] = 0.f;        // harness poisons d_out with 0xAA
}

__global__ __launch_bounds__(TPB)
__attribute__((amdgpu_waves_per_eu(2, 2)))   // 2 waves/EU -> 256-VGPR budget
void chamfer_min(
    const float4* __restrict__ P, unsigned int* __restrict__ dmin) {
  __shared__ float4 tile[JT];
  const int dir = blockIdx.z;                         // 0: query=pc1, 1: query=pc2
  const float4* __restrict__ Q = P + (size_t)dir * N_PTS;
  const float4* __restrict__ T = P + (size_t)(1 - dir) * N_PTS;
  unsigned int* __restrict__ out = dmin + (size_t)dir * N_PTS;

  const int jbase = blockIdx.x * JT;
  for (int t = threadIdx.x; t < JT; t += TPB)
    tile[t] = T[jbase + t];
  __syncthreads();

  const int i0 = blockIdx.y * (TPB * IP) + threadIdx.x * IP;

  // --- per-thread state: 40 NAMED scalars (no arrays -> no alloca) ---
#define DECL(k) float nx##k, ny##k, nz##k, cw##k, vmin##k;
  DECL(0) DECL(1) DECL(2) DECL(3) DECL(4) DECL(5) DECL(6) DECL(7)
#undef DECL
#define LOADQ(k) { float4 p = Q[i0 + k]; \
    nx##k = -p.x; ny##k = -p.y; nz##k = -p.z; cw##k = p.w; \
    vmin##k = 3.0e38f; }
  LOADQ(0) LOADQ(1) LOADQ(2) LOADQ(3) LOADQ(4) LOADQ(5) LOADQ(6) LOADQ(7)
#undef LOADQ

  // min_j (c_j - dot_ij); h_i drops out of the argmin.
  // vmin = min(vmin, va, vb) in ONE v_min3 (data NaN-free; fminf would
  // emit v_max canonicalization + no min3 formation).
#define PT(k) { \
    float va = fmaf(nx##k, qa.x, qa.w); \
    va = fmaf(ny##k, qa.y, va); \
    va = fmaf(nz##k, qa.z, va); \
    float vb = fmaf(nx##k, qb.x, qb.w); \
    vb = fmaf(ny##k, qb.y, vb); \
    vb = fmaf(nz##k, qb.z, vb); \
    asm("v_min3_f32 %0, %1, %2, %0" : "+v"(vmin##k) : "v"(va), "v"(vb)); }

#pragma unroll 8
  for (int j = 0; j < JT; j += 2) {
    float4 qa = tile[j];
    float4 qb = tile[j + 1];
    PT(0) PT(1) PT(2) PT(3) PT(4) PT(5) PT(6) PT(7)
  }
#undef PT

#define STORE(k) { \
    float d2 = fmaxf(0.f, 2.f * (cw##k + vmin##k)); \
    atomicMin(&out[i0 + k], __float_as_uint(d2)); }
  STORE(0) STORE(1) STORE(2) STORE(3) STORE(4) STORE(5) STORE(6) STORE(7)
#undef STORE
}

__global__ __launch_bounds__(TPB) void chamfer_reduce(
    const unsigned int* __restrict__ dmin, float* __restrict__ outp) {
  float s = 0.f;
  for (int i = blockIdx.x * TPB + threadIdx.x; i < 2 * N_PTS; i += REDB * TPB)
    s += sqrtf(__uint_as_float(dmin[i]));
#pragma unroll
  for (int off = 32; off > 0; off >>= 1)
    s += __shfl_down(s, off, 64);
  __shared__ float partial[TPB / 64];
  if ((threadIdx.x & 63) == 0) partial[threadIdx.x >> 6] = s;
  __syncthreads();
  if (threadIdx.x == 0) {
    float t = 0.f;
    for (int w = 0; w < TPB / 64; ++w) t += partial[w];
    // mean(dist1) + mean(dist2) = (sum of all 2N nn-distances) / N
    atomicAdd(outp, t * (1.0f / (float)N_PTS));
  }
}

extern "C" void kernel_launch(void* const* d_in, const int* in_sizes, int n_in,
                              void* d_out, int out_size, void* d_ws, size_t ws_size,
                              hipStream_t stream) {
  const float* pc1 = (const float*)d_in[0];
  const float* pc2 = (const float*)d_in[1];
  // ws layout: P[2N] float4 (512 KB) | dmin[2N] uint (128 KB)
  float4* P = (float4*)d_ws;
  unsigned int* dmin = (unsigned int*)((char*)d_ws + (size_t)2 * N_PTS * sizeof(float4));
  float* outp = (float*)d_out;

  chamfer_pack<<<(2 * N_PTS) / TPB, TPB, 0, stream>>>(pc1, pc2, P, dmin, outp);
  chamfer_min<<<dim3(JS, IBLK, 2), TPB, 0, stream>>>(P, dmin);
  chamfer_reduce<<<REDB, TPB, 0, stream>>>(dmin, outp);
}